// Round 10
// baseline (330.847 us; speedup 1.0000x reference)
//
#include <hip/hip_runtime.h>

typedef __bf16 bf16;
typedef __bf16 bf16x2_t __attribute__((ext_vector_type(2)));
typedef __bf16 bf16x4_t __attribute__((ext_vector_type(4)));
typedef __bf16 bf16x8 __attribute__((ext_vector_type(8)));
typedef float  f32x4  __attribute__((ext_vector_type(4)));

__device__ __forceinline__ void async16(const void* g, void* l) {
  __builtin_amdgcn_global_load_lds(
      (__attribute__((address_space(1))) void*)(g),
      (__attribute__((address_space(3))) void*)(l), 16, 0, 0);
}

__device__ __forceinline__ f32x4 mfma16(bf16x8 a, bf16x8 b, f32x4 c) {
  return __builtin_amdgcn_mfma_f32_16x16x32_bf16(a, b, c, 0, 0, 0);
}

// ------- fused prep: weight transposes + hs cvt + router partials + router ----
// blocks 0..2303: transpose tiles. blocks 2304..2559: cvt+partial for (b,g);
// the LAST cvt block of each batch (device-scope counter) runs the full router
// stage-2 for that batch (mean -> logits -> top-6 -> mask + actH). Canonical
// threadfence-reduction pattern; no spin-waits (no deadlock possible).
__global__ __launch_bounds__(256) void prep_k(
    const float* __restrict__ hs, bf16* __restrict__ hsb, float* __restrict__ partial,
    const float* __restrict__ s0, const float* __restrict__ s1,
    const float* __restrict__ s2, const float* __restrict__ s3,
    bf16* __restrict__ d0, bf16* __restrict__ d1,
    bf16* __restrict__ d2, bf16* __restrict__ d3,
    const float* __restrict__ Wr, const float* __restrict__ br,
    int* __restrict__ rcnt, float* __restrict__ mask, int* __restrict__ actH) {
  __shared__ bf16 tile[32][33];
  __shared__ float mean_s[768];
  __shared__ float red[4][12];
  __shared__ float lg[12];
  __shared__ int lastf;
  int id = blockIdx.x;
  int t = threadIdx.x;
  if (id < 2304) {
    int z = id / 576, rem = id % 576;
    int by = rem / 24, bx = rem % 24;
    const float* in = (z == 0) ? s0 : (z == 1) ? s1 : (z == 2) ? s2 : s3;
    bf16* out       = (z == 0) ? d0 : (z == 1) ? d1 : (z == 2) ? d2 : d3;
    int c0 = bx * 32, r0 = by * 32;
#pragma unroll
    for (int i = 0; i < 4; ++i) {
      int idx = t + i * 256;
      int r = idx >> 5, c = idx & 31;
      tile[r][c] = (bf16)in[(size_t)(r0 + r) * 768 + (c0 + c)];
    }
    __syncthreads();
#pragma unroll
    for (int i = 0; i < 4; ++i) {
      int idx = t + i * 256;
      int r = idx >> 5, c = idx & 31;
      out[(size_t)(c0 + r) * 768 + (r0 + c)] = tile[c][r];
    }
    return;
  }
  int id2 = id - 2304;
  int b = id2 & 7, g = id2 >> 3;
  if (t < 192) {
    const float* p = hs  + ((size_t)b * 1024 + g * 32) * 768 + t * 4;
    bf16*        q = hsb + ((size_t)b * 1024 + g * 32) * 768 + t * 4;
    float4 a = {0.f, 0.f, 0.f, 0.f};
    for (int s = 0; s < 32; ++s) {
      float4 v = *(const float4*)(p + (size_t)s * 768);
      a.x += v.x; a.y += v.y; a.z += v.z; a.w += v.w;
      bf16x4_t o;
      o[0] = (bf16)v.x; o[1] = (bf16)v.y; o[2] = (bf16)v.z; o[3] = (bf16)v.w;
      *(bf16x4_t*)(q + (size_t)s * 768) = o;
    }
    *(float4*)(partial + ((size_t)b * 32 + g) * 768 + t * 4) = a;
  }
  __threadfence();
  __syncthreads();
  if (t == 0) lastf = (atomicAdd(&rcnt[b], 1) == 31) ? 1 : 0;
  __syncthreads();
  if (lastf == 0) return;
  __threadfence();
  // ---- router stage 2 for batch b (last block only) ----
  for (int c = t; c < 768; c += 256) {
    float a = 0.f;
    for (int gg = 0; gg < 32; ++gg) a += partial[((size_t)b * 32 + gg) * 768 + c];
    mean_s[c] = a * (1.0f / 1024.0f);
  }
  __syncthreads();
  int w = t >> 6;
  float a[12];
#pragma unroll
  for (int h = 0; h < 12; ++h) a[h] = 0.f;
#pragma unroll
  for (int j = 0; j < 3; ++j) {
    int c = t + j * 256;
    float m = mean_s[c];
    const float* wr = Wr + c * 12;
#pragma unroll
    for (int h = 0; h < 12; ++h) a[h] += m * wr[h];
  }
#pragma unroll
  for (int off = 1; off < 64; off <<= 1)
#pragma unroll
    for (int h = 0; h < 12; ++h) a[h] += __shfl_xor(a[h], off);
  if ((t & 63) == 0)
#pragma unroll
    for (int h = 0; h < 12; ++h) red[w][h] = a[h];
  __syncthreads();
  if (t == 0) {
#pragma unroll
    for (int h = 0; h < 12; ++h)
      lg[h] = br[h] + red[0][h] + red[1][h] + red[2][h] + red[3][h];
    unsigned chosen = 0;
    for (int j = 0; j < 6; ++j) {
      int bi = -1; float bv = -1e30f;
      for (int h = 0; h < 12; ++h)
        if (!((chosen >> h) & 1) && lg[h] > bv) { bv = lg[h]; bi = h; }
      chosen |= 1u << bi;
    }
    int k = 0;
    for (int h = 0; h < 12; ++h) {
      mask[b * 12 + h] = ((chosen >> h) & 1) ? 1.f : 0.f;
      if ((chosen >> h) & 1) actH[b * 6 + (k++)] = h;
    }
  }
}

// ------- QKV GEMM over ACTIVE head PAIRS: full 128x128 tiles ------------------
__global__ __launch_bounds__(256, 3) void gemm_qkv_k(
    const bf16* __restrict__ X, const bf16* __restrict__ Wcat,
    const float* __restrict__ bq, const float* __restrict__ bk, const float* __restrict__ bv,
    const int* __restrict__ actH,
    bf16* __restrict__ Qo, bf16* __restrict__ Ko, bf16* __restrict__ Vto) {
  __shared__ __align__(16) bf16 Al[128 * 64];
  __shared__ __align__(16) bf16 Bl[128 * 64];
  int mt64 = blockIdx.x;
  int sp   = blockIdx.y;
  int z    = blockIdx.z;
  int b    = mt64 >> 3;
  int h0   = actH[b * 6 + sp * 2];
  int h1   = actH[b * 6 + sp * 2 + 1];
  int m0   = mt64 * 128;

  const float* bia = (z == 0) ? bq : (z == 1) ? bk : bv;
  int t = threadIdx.x, w = t >> 6, lane = t & 63, lrow = lane & 15, quad = lane >> 4;
  int wm = (w >> 1) * 64, wn = (w & 1) * 64;

  int srow = t >> 3;
  int sch  = (t & 7) ^ (srow & 7);
  const bf16* aptr[4];
  const bf16* bptr[4];
#pragma unroll
  for (int i = 0; i < 4; ++i) {
    aptr[i] = X + (size_t)(m0 + i * 32 + srow) * 768 + sch * 8;
    int hh = (i < 2) ? h0 : h1;
    int rr = (i & 1) * 32 + srow;
    bptr[i] = Wcat + (size_t)(z * 768 + hh * 64 + rr) * 768 + sch * 8;
  }

  int ra_base = wm + lrow, rb_base = wn + lrow;
  const bf16* baA[2];
  const bf16* baB[2];
#pragma unroll
  for (int ks = 0; ks < 2; ++ks) {
    baA[ks] = &Al[ra_base * 64 + (((ks * 4 + quad) ^ (ra_base & 7)) * 8)];
    baB[ks] = &Bl[rb_base * 64 + (((ks * 4 + quad) ^ (rb_base & 7)) * 8)];
  }

  f32x4 acc[4][4];
#pragma unroll
  for (int a = 0; a < 4; ++a)
#pragma unroll
    for (int c = 0; c < 4; ++c) acc[a][c] = (f32x4){0.f, 0.f, 0.f, 0.f};

  for (int k0 = 0; k0 < 768; k0 += 64) {
#pragma unroll
    for (int i = 0; i < 4; ++i) {
      async16(aptr[i], &Al[(i * 256 + t) * 8]);
      aptr[i] += 64;
    }
#pragma unroll
    for (int i = 0; i < 4; ++i) {
      async16(bptr[i], &Bl[(i * 256 + t) * 8]);
      bptr[i] += 64;
    }
    __syncthreads();
    bf16x8 af[2][4], bfr[2][4];
#pragma unroll
    for (int ks = 0; ks < 2; ++ks)
#pragma unroll
      for (int i = 0; i < 4; ++i) {
        af[ks][i]  = *(const bf16x8*)(baA[ks] + i * 1024);
        bfr[ks][i] = *(const bf16x8*)(baB[ks] + i * 1024);
      }
#pragma unroll
    for (int ks = 0; ks < 2; ++ks)
#pragma unroll
      for (int mt = 0; mt < 4; ++mt)
#pragma unroll
        for (int nt2 = 0; nt2 < 4; ++nt2)
          acc[mt][nt2] = mfma16(af[ks][mt], bfr[ks][nt2], acc[mt][nt2]);
    __syncthreads();
  }

  float biasv[4];
#pragma unroll
  for (int nt2 = 0; nt2 < 4; ++nt2) {
    int nl = wn + nt2 * 16 + lrow;
    int hh = (nl >> 6) ? h1 : h0;
    biasv[nt2] = bia[hh * 64 + (nl & 63)];
  }

  if (z == 2) {
#pragma unroll
    for (int mt = 0; mt < 4; ++mt)
#pragma unroll
      for (int nt2 = 0; nt2 < 4; ++nt2) {
        int s = (m0 + wm + mt * 16 + quad * 4) & 1023;
        int nl = wn + nt2 * 16 + lrow;
        int hh = (nl >> 6) ? h1 : h0;
        int d = nl & 63;
        bf16x4_t pk;
#pragma unroll
        for (int r = 0; r < 4; ++r) pk[r] = (bf16)(acc[mt][nt2][r] + biasv[nt2]);
        *(bf16x4_t*)&Vto[(((size_t)b * 12 + hh) * 64 + d) * 1024 + s] = pk;
      }
  } else {
    bf16* Out = (z == 0) ? Qo : Ko;
#pragma unroll
    for (int mt = 0; mt < 4; ++mt)
#pragma unroll
      for (int nt2 = 0; nt2 < 4; ++nt2)
#pragma unroll
        for (int r = 0; r < 4; ++r) {
          int s = (m0 + wm + mt * 16 + quad * 4 + r) & 1023;
          int nl = wn + nt2 * 16 + lrow;
          int hh = (nl >> 6) ? h1 : h0;
          int d = nl & 63;
          Out[(((size_t)b * 12 + hh) * 1024 + s) * 64 + d] =
              (bf16)(acc[mt][nt2][r] + biasv[nt2]);
        }
  }
}

// ---------------- flash attention (R9: frozen structure + T5 + T13) -----------
__global__ __launch_bounds__(256, 3) void attn_k(
    const bf16* __restrict__ Q, const bf16* __restrict__ K, const bf16* __restrict__ Vt,
    const int* __restrict__ actH, bf16* __restrict__ ctx) {
  int ai = blockIdx.x, qt = blockIdx.y;
  int bb = ai / 6, slot = ai - bb * 6;
  int h = actH[bb * 6 + slot];
  int bh = bb * 12 + h;
  int t = threadIdx.x, w = t >> 6, lane = t & 63, lrow = lane & 15, quad = lane >> 4;

  __shared__ __align__(16) bf16 K_lds[128 * 64];
  __shared__ __align__(16) bf16 V_lds[64 * 128];
  __shared__ __align__(16) bf16 P_lds[4][16 * 136];

  const bf16* Qh = Q  + (size_t)bh * 65536;
  const bf16* Kh = K  + (size_t)bh * 65536;
  const bf16* Vh = Vt + (size_t)bh * 65536;

  bf16x8 qf[2][2];
#pragma unroll
  for (int mt = 0; mt < 2; ++mt)
#pragma unroll
    for (int ks = 0; ks < 2; ++ks)
      qf[mt][ks] = *(const bf16x8*)&Qh[(size_t)(qt * 128 + w * 32 + mt * 16 + lrow) * 64 + ks * 32 + quad * 8];

  f32x4 o_acc[2][4];
  float m_i[2][4], l_i[2][4];
#pragma unroll
  for (int mt = 0; mt < 2; ++mt) {
#pragma unroll
    for (int dt = 0; dt < 4; ++dt) o_acc[mt][dt] = (f32x4){0.f, 0.f, 0.f, 0.f};
#pragma unroll
    for (int r = 0; r < 4; ++r) { m_i[mt][r] = -INFINITY; l_i[mt][r] = 0.f; }
  }

  for (int kt = 0; kt < 8; ++kt) {
#pragma unroll
    for (int i = 0; i < 4; ++i) {
      int c = i * 256 + t;
      int r = c >> 3, ch = (c & 7) ^ (r & 7);
      async16(Kh + (size_t)kt * 8192 + r * 64 + ch * 8, &K_lds[c * 8]);
    }
#pragma unroll
    for (int i = 0; i < 4; ++i) {
      int c = i * 256 + t;
      int r = c >> 4, ch = (c & 15) ^ (r & 7);
      async16(Vh + (size_t)r * 1024 + kt * 128 + ch * 8, &V_lds[c * 8]);
    }
    __syncthreads();

#pragma unroll
    for (int mt = 0; mt < 2; ++mt) {
      f32x4 s_acc[8];
#pragma unroll
      for (int nt = 0; nt < 8; ++nt) s_acc[nt] = (f32x4){0.f, 0.f, 0.f, 0.f};
      __builtin_amdgcn_s_setprio(1);
#pragma unroll
      for (int nt = 0; nt < 8; ++nt) {
        int rb = nt * 16 + lrow;
#pragma unroll
        for (int ks = 0; ks < 2; ++ks) {
          bf16x8 kf = *(const bf16x8*)&K_lds[rb * 64 + (((ks * 4 + quad) ^ (rb & 7)) * 8)];
          s_acc[nt] = mfma16(qf[mt][ks], kf, s_acc[nt]);
        }
      }
      __builtin_amdgcn_s_setprio(0);
#pragma unroll
      for (int nt = 0; nt < 8; ++nt) s_acc[nt] = s_acc[nt] * 0.125f;

      float mx[4];
#pragma unroll
      for (int r = 0; r < 4; ++r) {
        float m = s_acc[0][r];
#pragma unroll
        for (int nt = 1; nt < 8; ++nt) m = fmaxf(m, s_acc[nt][r]);
        m = fmaxf(m, __shfl_xor(m, 1));
        m = fmaxf(m, __shfl_xor(m, 2));
        m = fmaxf(m, __shfl_xor(m, 4));
        m = fmaxf(m, __shfl_xor(m, 8));
        mx[r] = m;
      }
      bool grow = false;
#pragma unroll
      for (int r = 0; r < 4; ++r) grow = grow || (mx[r] > m_i[mt][r] + 8.f);
      if (__any(grow)) {
#pragma unroll
        for (int r = 0; r < 4; ++r) {
          float mold = m_i[mt][r];
          float mnew = fmaxf(mold, mx[r]);
          float alpha = __expf(mold - mnew);
          m_i[mt][r] = mnew;
          l_i[mt][r] *= alpha;
#pragma unroll
          for (int dt = 0; dt < 4; ++dt) o_acc[mt][dt][r] *= alpha;
        }
      }
#pragma unroll
      for (int r = 0; r < 4; ++r) {
        float mnew = m_i[mt][r];
        float rs = 0.f;
#pragma unroll
        for (int nt = 0; nt < 8; ++nt) {
          float pv = __expf(s_acc[nt][r] - mnew);
          rs += pv;
          P_lds[w][(quad * 4 + r) * 136 + nt * 16 + lrow] = (bf16)pv;
        }
        rs += __shfl_xor(rs, 1);
        rs += __shfl_xor(rs, 2);
        rs += __shfl_xor(rs, 4);
        rs += __shfl_xor(rs, 8);
        l_i[mt][r] += rs;
      }

      bf16x8 pf[4];
#pragma unroll
      for (int ks = 0; ks < 4; ++ks)
        pf[ks] = *(const bf16x8*)&P_lds[w][lrow * 136 + ks * 32 + quad * 8];
      __builtin_amdgcn_s_setprio(1);
#pragma unroll
      for (int dt = 0; dt < 4; ++dt) {
        int rv = dt * 16 + lrow;
#pragma unroll
        for (int ks = 0; ks < 4; ++ks) {
          bf16x8 vf = *(const bf16x8*)&V_lds[rv * 128 + (((ks * 4 + quad) ^ (rv & 7)) * 8)];
          o_acc[mt][dt] = mfma16(pf[ks], vf, o_acc[mt][dt]);
        }
      }
      __builtin_amdgcn_s_setprio(0);
    }
    __syncthreads();
  }

#pragma unroll
  for (int mt = 0; mt < 2; ++mt)
#pragma unroll
    for (int r = 0; r < 4; ++r) {
      float inv = 1.0f / l_i[mt][r];
      int s = qt * 128 + w * 32 + mt * 16 + quad * 4 + r;
#pragma unroll
      for (int dt = 0; dt < 4; ++dt) {
        int d = dt * 16 + lrow;
        ctx[((size_t)(bb * 1024 + s)) * 768 + h * 64 + d] = (bf16)(o_acc[mt][dt][r] * inv);
      }
    }
}

// ------- out-proj GEMM + fused LayerNorm (last block of each 128-row group) ---
// The 6 blocks sharing rows [g*128,(g+1)*128) count down via gcnt[g]; the last
// one LN-normalizes those rows (float4 loads of L2/L3-hot Xb) into d_out.
// gcnt==nullptr disables the fusion (fallback path uses separate ln_k).
__global__ __launch_bounds__(256, 3) void gemm_out_k(
    const bf16* __restrict__ Cx, const bf16* __restrict__ Wot,
    const float* __restrict__ bo, const float* __restrict__ res,
    const float* __restrict__ mask,
    float* __restrict__ xo,
    int* __restrict__ gcnt, const float* __restrict__ lng,
    const float* __restrict__ lnb, float* __restrict__ outp) {
  __shared__ __align__(16) bf16 Al[128 * 64];
  __shared__ __align__(16) bf16 Bl[128 * 64];
  __shared__ int lastf;
  int bid = blockIdx.x;
  int xcd = bid & 7, idx = bid >> 3;
  int nt = idx % 6, mt8 = idx / 6;
  int m0 = (mt8 * 8 + xcd) * 128;
  int n0 = nt * 128;
  int t = threadIdx.x, w = t >> 6, lane = t & 63, lrow = lane & 15, quad = lane >> 4;
  int wm = (w >> 1) * 64, wn = (w & 1) * 64;

  int bb = m0 >> 10;
  unsigned am = 0;
#pragma unroll
  for (int hh = 0; hh < 12; ++hh)
    am |= (mask[bb * 12 + hh] != 0.f) ? (1u << hh) : 0u;

  int srow = t >> 3;
  int sch  = (t & 7) ^ (srow & 7);
  const bf16* aptr[4];
  const bf16* bptr[4];
#pragma unroll
  for (int i = 0; i < 4; ++i) {
    aptr[i] = Cx  + (size_t)(m0 + i * 32 + srow) * 768 + sch * 8;
    bptr[i] = Wot + (size_t)(n0 + i * 32 + srow) * 768 + sch * 8;
  }
  int ra_base = wm + lrow, rb_base = wn + lrow;
  const bf16* baA[2];
  const bf16* baB[2];
#pragma unroll
  for (int ks = 0; ks < 2; ++ks) {
    baA[ks] = &Al[ra_base * 64 + (((ks * 4 + quad) ^ (ra_base & 7)) * 8)];
    baB[ks] = &Bl[rb_base * 64 + (((ks * 4 + quad) ^ (rb_base & 7)) * 8)];
  }

  f32x4 acc[4][4];
#pragma unroll
  for (int a = 0; a < 4; ++a)
#pragma unroll
    for (int b = 0; b < 4; ++b) acc[a][b] = (f32x4){0.f, 0.f, 0.f, 0.f};

  for (int k0 = 0; k0 < 768; k0 += 64) {
    if (am & (1u << (k0 >> 6))) {
#pragma unroll
      for (int i = 0; i < 4; ++i) async16(aptr[i], &Al[(i * 256 + t) * 8]);
#pragma unroll
      for (int i = 0; i < 4; ++i) async16(bptr[i], &Bl[(i * 256 + t) * 8]);
      __syncthreads();
      bf16x8 af[2][4], bfr[2][4];
#pragma unroll
      for (int ks = 0; ks < 2; ++ks)
#pragma unroll
        for (int i = 0; i < 4; ++i) {
          af[ks][i]  = *(const bf16x8*)(baA[ks] + i * 1024);
          bfr[ks][i] = *(const bf16x8*)(baB[ks] + i * 1024);
        }
#pragma unroll
      for (int ks = 0; ks < 2; ++ks)
#pragma unroll
        for (int mt = 0; mt < 4; ++mt)
#pragma unroll
          for (int nt2 = 0; nt2 < 4; ++nt2)
            acc[mt][nt2] = mfma16(af[ks][mt], bfr[ks][nt2], acc[mt][nt2]);
      __syncthreads();
    }
#pragma unroll
    for (int i = 0; i < 4; ++i) { aptr[i] += 64; bptr[i] += 64; }
  }

  float biasv[4];
#pragma unroll
  for (int nt2 = 0; nt2 < 4; ++nt2) biasv[nt2] = bo[n0 + wn + nt2 * 16 + lrow];

#pragma unroll
  for (int mt = 0; mt < 4; ++mt)
#pragma unroll
    for (int nt2 = 0; nt2 < 4; ++nt2)
#pragma unroll
      for (int r = 0; r < 4; ++r) {
        int m = m0 + wm + mt * 16 + quad * 4 + r;
        int n = n0 + wn + nt2 * 16 + lrow;
        xo[(size_t)m * 768 + n] = acc[mt][nt2][r] + biasv[nt2] + res[(size_t)m * 768 + n];
      }

  if (!gcnt) return;
  __threadfence();
  __syncthreads();
  if (t == 0) lastf = (atomicAdd(&gcnt[mt8 * 8 + xcd], 1) == 5) ? 1 : 0;
  __syncthreads();
  if (lastf == 0) return;
  __threadfence();
  // ---- fused LN over rows [m0, m0+128): 4 waves x 32 rows, float4 I/O ----
  const float4* g4 = (const float4*)lng;
  const float4* b4 = (const float4*)lnb;
  for (int i = 0; i < 32; ++i) {
    int row = m0 + w * 32 + i;
    const float4* xr4 = (const float4*)(xo + (size_t)row * 768);
    float4 xv0 = xr4[lane], xv1 = xr4[lane + 64], xv2 = xr4[lane + 128];
    float s  = xv0.x + xv0.y + xv0.z + xv0.w
             + xv1.x + xv1.y + xv1.z + xv1.w
             + xv2.x + xv2.y + xv2.z + xv2.w;
    float s2 = xv0.x*xv0.x + xv0.y*xv0.y + xv0.z*xv0.z + xv0.w*xv0.w
             + xv1.x*xv1.x + xv1.y*xv1.y + xv1.z*xv1.z + xv1.w*xv1.w
             + xv2.x*xv2.x + xv2.y*xv2.y + xv2.z*xv2.z + xv2.w*xv2.w;
#pragma unroll
    for (int off = 32; off > 0; off >>= 1) {
      s  += __shfl_xor(s, off);
      s2 += __shfl_xor(s2, off);
    }
    float mu = s * (1.0f / 768.0f);
    float var = s2 * (1.0f / 768.0f) - mu * mu;
    float rsq = rsqrtf(var + 1e-12f);
    float4* or4 = (float4*)(outp + (size_t)row * 768);
    float4 gv, bv, o;
    gv = g4[lane];       bv = b4[lane];
    o.x = (xv0.x - mu) * rsq * gv.x + bv.x; o.y = (xv0.y - mu) * rsq * gv.y + bv.y;
    o.z = (xv0.z - mu) * rsq * gv.z + bv.z; o.w = (xv0.w - mu) * rsq * gv.w + bv.w;
    or4[lane] = o;
    gv = g4[lane + 64];  bv = b4[lane + 64];
    o.x = (xv1.x - mu) * rsq * gv.x + bv.x; o.y = (xv1.y - mu) * rsq * gv.y + bv.y;
    o.z = (xv1.z - mu) * rsq * gv.z + bv.z; o.w = (xv1.w - mu) * rsq * gv.w + bv.w;
    or4[lane + 64] = o;
    gv = g4[lane + 128]; bv = b4[lane + 128];
    o.x = (xv2.x - mu) * rsq * gv.x + bv.x; o.y = (xv2.y - mu) * rsq * gv.y + bv.y;
    o.z = (xv2.z - mu) * rsq * gv.z + bv.z; o.w = (xv2.w - mu) * rsq * gv.w + bv.w;
    or4[lane + 128] = o;
  }
}

// ---------------- LayerNorm (fallback path only) ------------------------------
__global__ __launch_bounds__(256) void ln_k(const float* __restrict__ x,
                                            const float* __restrict__ g,
                                            const float* __restrict__ be,
                                            float* __restrict__ out) {
  int row = blockIdx.x, t = threadIdx.x;
  const float* xr = x + (size_t)row * 768;
  float v0 = xr[t], v1 = xr[t + 256], v2 = xr[t + 512];
  float s = v0 + v1 + v2;
  float s2 = v0 * v0 + v1 * v1 + v2 * v2;
#pragma unroll
  for (int off = 32; off > 0; off >>= 1) {
    s  += __shfl_down(s, off);
    s2 += __shfl_down(s2, off);
  }
  __shared__ float red[8];
  if ((t & 63) == 0) { red[(t >> 6) * 2] = s; red[(t >> 6) * 2 + 1] = s2; }
  __syncthreads();
  if (t == 0) {
    float a = 0.f, b2 = 0.f;
    for (int i = 0; i < 4; ++i) { a += red[2 * i]; b2 += red[2 * i + 1]; }
    float mu = a * (1.0f / 768.0f);
    float var = b2 * (1.0f / 768.0f) - mu * mu;
    red[0] = mu;
    red[1] = rsqrtf(var + 1e-12f);
  }
  __syncthreads();
  float mu = red[0], rs = red[1];
  out[(size_t)row * 768 + t]       = (v0 - mu) * rs * g[t]       + be[t];
  out[(size_t)row * 768 + t + 256] = (v1 - mu) * rs * g[t + 256] + be[t + 256];
  out[(size_t)row * 768 + t + 512] = (v2 - mu) * rs * g[t + 512] + be[t + 512];
}

// ---------------- host launcher ----------------------------------------------
extern "C" void kernel_launch(void* const* d_in, const int* in_sizes, int n_in,
                              void* d_out, int out_size, void* d_ws, size_t ws_size,
                              hipStream_t stream) {
  const float* hs  = (const float*)d_in[0];
  const float* Wq  = (const float*)d_in[1];
  const float* bq  = (const float*)d_in[2];
  const float* Wk  = (const float*)d_in[3];
  const float* bk  = (const float*)d_in[4];
  const float* Wv  = (const float*)d_in[5];
  const float* bv  = (const float*)d_in[6];
  const float* Wr  = (const float*)d_in[7];
  const float* br  = (const float*)d_in[8];
  const float* Wo  = (const float*)d_in[9];
  const float* bo  = (const float*)d_in[10];
  const float* lng = (const float*)d_in[11];
  const float* lnb = (const float*)d_in[12];
  float* out = (float*)d_out;
  dim3 blk(256);

  // ---- workspace layout ----
  char* p = (char*)d_ws;
  float* maskp = (float*)p; p += 512;
  int*   actI  = (int*)p;   p += 256;
  int*   rcnt  = (int*)p;   p += 64;    // 8 ints
  int*   gcnt  = (int*)p;   p += 256;   // 64 ints (contiguous with rcnt)
  float* partial = (float*)p; p += (size_t)8 * 32 * 768 * 4;   // 768 KB
  bf16* hsb  = (bf16*)p; p += (size_t)8192 * 768 * 2;          // 12.6 MB (doubles as Ctx)
  bf16* Wcat = (bf16*)p; p += (size_t)2304 * 768 * 2;          // 3.5 MB
  bf16* Wot  = (bf16*)p; p += (size_t)768 * 768 * 2;           // 1.2 MB

  hipMemsetAsync(rcnt, 0, 320, stream);   // rcnt + gcnt

  prep_k<<<dim3(2560), blk, 0, stream>>>(hs, hsb, partial,
      Wq, Wk, Wv, Wo, Wcat, Wcat + 768 * 768, Wcat + 1536 * 768, Wot,
      Wr, br, rcnt, maskp, actI);

  size_t used_common = (size_t)(p - (char*)d_ws);
  size_t need_big = used_common + 3 * (size_t)8192 * 768 * 2;

  if (ws_size >= need_big) {
    char* qk_base = p;
    bf16* Qb  = (bf16*)p; p += (size_t)8192 * 768 * 2;
    bf16* Kb  = (bf16*)p; p += (size_t)8192 * 768 * 2;
    bf16* Vtb = (bf16*)p;
    float* Xb = (float*)qk_base;   // aliases Qb+Kb (dead after attn)
    bf16* Ctx = hsb;               // hsb dead after gemm_qkv; attn writes here

    gemm_qkv_k<<<dim3(64, 3, 3), blk, 0, stream>>>(hsb, Wcat, bq, bk, bv, actI, Qb, Kb, Vtb);
    attn_k<<<dim3(48, 8), blk, 0, stream>>>(Qb, Kb, Vtb, actI, Ctx);
    gemm_out_k<<<dim3(8 * 8 * 6), blk, 0, stream>>>(Ctx, Wot, bo, hs, maskp, Xb,
                                                    gcnt, lng, lnb, out);
  } else {
    bf16* Qb  = (bf16*)p; p += (size_t)1024 * 768 * 2;
    bf16* Kb  = (bf16*)p; p += (size_t)1024 * 768 * 2;
    bf16* Vtb = (bf16*)p; p += (size_t)1024 * 768 * 2;
    bf16* Ctx = (bf16*)p; p += (size_t)1024 * 768 * 2;
    float* Xb = (float*)p; p += (size_t)1024 * 768 * 4;

    for (int b = 0; b < 8; ++b) {
      const bf16* hsb_b = hsb + (size_t)b * 1024 * 768;
      const float* hs_b = hs + (size_t)b * 1024 * 768;
      float* outb = out + (size_t)b * 1024 * 768;
      gemm_qkv_k<<<dim3(8, 3, 3), blk, 0, stream>>>(hsb_b, Wcat, bq, bk, bv, actI + b * 6, Qb, Kb, Vtb);
      attn_k<<<dim3(6, 8), blk, 0, stream>>>(Qb, Kb, Vtb, actI + b * 6, Ctx);
      gemm_out_k<<<dim3(8 * 1 * 6), blk, 0, stream>>>(Ctx, Wot, bo, hs_b, maskp + b * 12, Xb,
                                                      (int*)nullptr, lng, lnb, outb);
      ln_k<<<dim3(1024), blk, 0, stream>>>(Xb, lng, lnb, outb);
    }
  }
}

// Round 11
// 210.763 us; speedup vs baseline: 1.5698x; 1.5698x over previous
//
#include <hip/hip_runtime.h>

typedef __bf16 bf16;
typedef __bf16 bf16x2_t __attribute__((ext_vector_type(2)));
typedef __bf16 bf16x4_t __attribute__((ext_vector_type(4)));
typedef __bf16 bf16x8 __attribute__((ext_vector_type(8)));
typedef float  f32x4  __attribute__((ext_vector_type(4)));

__device__ __forceinline__ void async16(const void* g, void* l) {
  __builtin_amdgcn_global_load_lds(
      (__attribute__((address_space(1))) void*)(g),
      (__attribute__((address_space(3))) void*)(l), 16, 0, 0);
}

__device__ __forceinline__ f32x4 mfma16(bf16x8 a, bf16x8 b, f32x4 c) {
  return __builtin_amdgcn_mfma_f32_16x16x32_bf16(a, b, c, 0, 0, 0);
}

// ------- fused prep: 4 weight transposes + hs cvt + router partial sums -------
// blocks 0..2303: transpose tiles; 2304..2559: cvt_router. (R9-proven; the
// R10 experiment of absorbing router stage-2 here was part of a regression.)
__global__ __launch_bounds__(256) void prep_k(
    const float* __restrict__ hs, bf16* __restrict__ hsb, float* __restrict__ partial,
    const float* __restrict__ s0, const float* __restrict__ s1,
    const float* __restrict__ s2, const float* __restrict__ s3,
    bf16* __restrict__ d0, bf16* __restrict__ d1,
    bf16* __restrict__ d2, bf16* __restrict__ d3) {
  __shared__ bf16 tile[32][33];
  int id = blockIdx.x;
  int t = threadIdx.x;
  if (id < 2304) {
    int z = id / 576, rem = id % 576;
    int by = rem / 24, bx = rem % 24;
    const float* in = (z == 0) ? s0 : (z == 1) ? s1 : (z == 2) ? s2 : s3;
    bf16* out       = (z == 0) ? d0 : (z == 1) ? d1 : (z == 2) ? d2 : d3;
    int c0 = bx * 32, r0 = by * 32;
#pragma unroll
    for (int i = 0; i < 4; ++i) {
      int idx = t + i * 256;
      int r = idx >> 5, c = idx & 31;
      tile[r][c] = (bf16)in[(size_t)(r0 + r) * 768 + (c0 + c)];
    }
    __syncthreads();
#pragma unroll
    for (int i = 0; i < 4; ++i) {
      int idx = t + i * 256;
      int r = idx >> 5, c = idx & 31;
      out[(size_t)(c0 + r) * 768 + (r0 + c)] = tile[c][r];
    }
  } else {
    int id2 = id - 2304;
    int b = id2 & 7, g = id2 >> 3;
    if (t >= 192) return;
    const float* p = hs  + ((size_t)b * 1024 + g * 32) * 768 + t * 4;
    bf16*        q = hsb + ((size_t)b * 1024 + g * 32) * 768 + t * 4;
    float4 a = {0.f, 0.f, 0.f, 0.f};
    for (int s = 0; s < 32; ++s) {
      float4 v = *(const float4*)(p + (size_t)s * 768);
      a.x += v.x; a.y += v.y; a.z += v.z; a.w += v.w;
      bf16x4_t o;
      o[0] = (bf16)v.x; o[1] = (bf16)v.y; o[2] = (bf16)v.z; o[3] = (bf16)v.w;
      *(bf16x4_t*)(q + (size_t)s * 768) = o;
    }
    *(float4*)(partial + ((size_t)b * 32 + g) * 768 + t * 4) = a;
  }
}

// ---- router stage 2: mean -> logits (parallel dot) -> top-6 mask + head list -
__global__ __launch_bounds__(256) void router_final_k(const float* __restrict__ Wr,
                                                      const float* __restrict__ br,
                                                      const float* __restrict__ partial,
                                                      float* __restrict__ mask,
                                                      int* __restrict__ actH) {
  int b = blockIdx.x, t = threadIdx.x;
  int w = t >> 6;
  __shared__ float mean_s[768];
  __shared__ float red[4][12];
  __shared__ float lg[12];
  for (int c = t; c < 768; c += 256) {
    float a = 0.f;
    for (int g = 0; g < 32; ++g) a += partial[((size_t)b * 32 + g) * 768 + c];
    mean_s[c] = a * (1.0f / 1024.0f);
  }
  __syncthreads();
  float a[12];
#pragma unroll
  for (int h = 0; h < 12; ++h) a[h] = 0.f;
#pragma unroll
  for (int j = 0; j < 3; ++j) {
    int c = t + j * 256;
    float m = mean_s[c];
    const float* wr = Wr + c * 12;
#pragma unroll
    for (int h = 0; h < 12; ++h) a[h] += m * wr[h];
  }
#pragma unroll
  for (int off = 1; off < 64; off <<= 1)
#pragma unroll
    for (int h = 0; h < 12; ++h) a[h] += __shfl_xor(a[h], off);
  if ((t & 63) == 0)
#pragma unroll
    for (int h = 0; h < 12; ++h) red[w][h] = a[h];
  __syncthreads();
  if (t == 0) {
#pragma unroll
    for (int h = 0; h < 12; ++h)
      lg[h] = br[h] + red[0][h] + red[1][h] + red[2][h] + red[3][h];
    unsigned chosen = 0;
    for (int j = 0; j < 6; ++j) {
      int bi = -1; float bv = -1e30f;
      for (int h = 0; h < 12; ++h)
        if (!((chosen >> h) & 1) && lg[h] > bv) { bv = lg[h]; bi = h; }
      chosen |= 1u << bi;
    }
    int k = 0;
    for (int h = 0; h < 12; ++h) {
      mask[b * 12 + h] = ((chosen >> h) & 1) ? 1.f : 0.f;
      if ((chosen >> h) & 1) actH[b * 6 + (k++)] = h;
    }
  }
}

// ------- QKV GEMM over ACTIVE head PAIRS: full 128x128 tiles ------------------
__global__ __launch_bounds__(256, 3) void gemm_qkv_k(
    const bf16* __restrict__ X, const bf16* __restrict__ Wcat,
    const float* __restrict__ bq, const float* __restrict__ bk, const float* __restrict__ bv,
    const int* __restrict__ actH,
    bf16* __restrict__ Qo, bf16* __restrict__ Ko, bf16* __restrict__ Vto) {
  __shared__ __align__(16) bf16 Al[128 * 64];
  __shared__ __align__(16) bf16 Bl[128 * 64];
  int mt64 = blockIdx.x;
  int sp   = blockIdx.y;
  int z    = blockIdx.z;
  int b    = mt64 >> 3;
  int h0   = actH[b * 6 + sp * 2];
  int h1   = actH[b * 6 + sp * 2 + 1];
  int m0   = mt64 * 128;

  const float* bia = (z == 0) ? bq : (z == 1) ? bk : bv;
  int t = threadIdx.x, w = t >> 6, lane = t & 63, lrow = lane & 15, quad = lane >> 4;
  int wm = (w >> 1) * 64, wn = (w & 1) * 64;

  int srow = t >> 3;
  int sch  = (t & 7) ^ (srow & 7);
  const bf16* aptr[4];
  const bf16* bptr[4];
#pragma unroll
  for (int i = 0; i < 4; ++i) {
    aptr[i] = X + (size_t)(m0 + i * 32 + srow) * 768 + sch * 8;
    int hh = (i < 2) ? h0 : h1;
    int rr = (i & 1) * 32 + srow;
    bptr[i] = Wcat + (size_t)(z * 768 + hh * 64 + rr) * 768 + sch * 8;
  }

  int ra_base = wm + lrow, rb_base = wn + lrow;
  const bf16* baA[2];
  const bf16* baB[2];
#pragma unroll
  for (int ks = 0; ks < 2; ++ks) {
    baA[ks] = &Al[ra_base * 64 + (((ks * 4 + quad) ^ (ra_base & 7)) * 8)];
    baB[ks] = &Bl[rb_base * 64 + (((ks * 4 + quad) ^ (rb_base & 7)) * 8)];
  }

  f32x4 acc[4][4];
#pragma unroll
  for (int a = 0; a < 4; ++a)
#pragma unroll
    for (int c = 0; c < 4; ++c) acc[a][c] = (f32x4){0.f, 0.f, 0.f, 0.f};

  for (int k0 = 0; k0 < 768; k0 += 64) {
#pragma unroll
    for (int i = 0; i < 4; ++i) {
      async16(aptr[i], &Al[(i * 256 + t) * 8]);
      aptr[i] += 64;
    }
#pragma unroll
    for (int i = 0; i < 4; ++i) {
      async16(bptr[i], &Bl[(i * 256 + t) * 8]);
      bptr[i] += 64;
    }
    __syncthreads();
    bf16x8 af[2][4], bfr[2][4];
#pragma unroll
    for (int ks = 0; ks < 2; ++ks)
#pragma unroll
      for (int i = 0; i < 4; ++i) {
        af[ks][i]  = *(const bf16x8*)(baA[ks] + i * 1024);
        bfr[ks][i] = *(const bf16x8*)(baB[ks] + i * 1024);
      }
#pragma unroll
    for (int ks = 0; ks < 2; ++ks)
#pragma unroll
      for (int mt = 0; mt < 4; ++mt)
#pragma unroll
        for (int nt2 = 0; nt2 < 4; ++nt2)
          acc[mt][nt2] = mfma16(af[ks][mt], bfr[ks][nt2], acc[mt][nt2]);
    __syncthreads();
  }

  float biasv[4];
#pragma unroll
  for (int nt2 = 0; nt2 < 4; ++nt2) {
    int nl = wn + nt2 * 16 + lrow;
    int hh = (nl >> 6) ? h1 : h0;
    biasv[nt2] = bia[hh * 64 + (nl & 63)];
  }

  if (z == 2) {
#pragma unroll
    for (int mt = 0; mt < 4; ++mt)
#pragma unroll
      for (int nt2 = 0; nt2 < 4; ++nt2) {
        int s = (m0 + wm + mt * 16 + quad * 4) & 1023;
        int nl = wn + nt2 * 16 + lrow;
        int hh = (nl >> 6) ? h1 : h0;
        int d = nl & 63;
        bf16x4_t pk;
#pragma unroll
        for (int r = 0; r < 4; ++r) pk[r] = (bf16)(acc[mt][nt2][r] + biasv[nt2]);
        *(bf16x4_t*)&Vto[(((size_t)b * 12 + hh) * 64 + d) * 1024 + s] = pk;
      }
  } else {
    bf16* Out = (z == 0) ? Qo : Ko;
#pragma unroll
    for (int mt = 0; mt < 4; ++mt)
#pragma unroll
      for (int nt2 = 0; nt2 < 4; ++nt2)
#pragma unroll
        for (int r = 0; r < 4; ++r) {
          int s = (m0 + wm + mt * 16 + quad * 4 + r) & 1023;
          int nl = wn + nt2 * 16 + lrow;
          int hh = (nl >> 6) ? h1 : h0;
          int d = nl & 63;
          Out[(((size_t)b * 12 + hh) * 1024 + s) * 64 + d] =
              (bf16)(acc[mt][nt2][r] + biasv[nt2]);
        }
  }
}

// ---------------- flash attention (R9: frozen structure + T5 + T13) -----------
__global__ __launch_bounds__(256, 3) void attn_k(
    const bf16* __restrict__ Q, const bf16* __restrict__ K, const bf16* __restrict__ Vt,
    const int* __restrict__ actH, bf16* __restrict__ ctx) {
  int ai = blockIdx.x, qt = blockIdx.y;
  int bb = ai / 6, slot = ai - bb * 6;
  int h = actH[bb * 6 + slot];
  int bh = bb * 12 + h;
  int t = threadIdx.x, w = t >> 6, lane = t & 63, lrow = lane & 15, quad = lane >> 4;

  __shared__ __align__(16) bf16 K_lds[128 * 64];
  __shared__ __align__(16) bf16 V_lds[64 * 128];
  __shared__ __align__(16) bf16 P_lds[4][16 * 136];

  const bf16* Qh = Q  + (size_t)bh * 65536;
  const bf16* Kh = K  + (size_t)bh * 65536;
  const bf16* Vh = Vt + (size_t)bh * 65536;

  bf16x8 qf[2][2];
#pragma unroll
  for (int mt = 0; mt < 2; ++mt)
#pragma unroll
    for (int ks = 0; ks < 2; ++ks)
      qf[mt][ks] = *(const bf16x8*)&Qh[(size_t)(qt * 128 + w * 32 + mt * 16 + lrow) * 64 + ks * 32 + quad * 8];

  f32x4 o_acc[2][4];
  float m_i[2][4], l_i[2][4];
#pragma unroll
  for (int mt = 0; mt < 2; ++mt) {
#pragma unroll
    for (int dt = 0; dt < 4; ++dt) o_acc[mt][dt] = (f32x4){0.f, 0.f, 0.f, 0.f};
#pragma unroll
    for (int r = 0; r < 4; ++r) { m_i[mt][r] = -INFINITY; l_i[mt][r] = 0.f; }
  }

  for (int kt = 0; kt < 8; ++kt) {
#pragma unroll
    for (int i = 0; i < 4; ++i) {
      int c = i * 256 + t;
      int r = c >> 3, ch = (c & 7) ^ (r & 7);
      async16(Kh + (size_t)kt * 8192 + r * 64 + ch * 8, &K_lds[c * 8]);
    }
#pragma unroll
    for (int i = 0; i < 4; ++i) {
      int c = i * 256 + t;
      int r = c >> 4, ch = (c & 15) ^ (r & 7);
      async16(Vh + (size_t)r * 1024 + kt * 128 + ch * 8, &V_lds[c * 8]);
    }
    __syncthreads();

#pragma unroll
    for (int mt = 0; mt < 2; ++mt) {
      f32x4 s_acc[8];
#pragma unroll
      for (int nt = 0; nt < 8; ++nt) s_acc[nt] = (f32x4){0.f, 0.f, 0.f, 0.f};
      __builtin_amdgcn_s_setprio(1);
#pragma unroll
      for (int nt = 0; nt < 8; ++nt) {
        int rb = nt * 16 + lrow;
#pragma unroll
        for (int ks = 0; ks < 2; ++ks) {
          bf16x8 kf = *(const bf16x8*)&K_lds[rb * 64 + (((ks * 4 + quad) ^ (rb & 7)) * 8)];
          s_acc[nt] = mfma16(qf[mt][ks], kf, s_acc[nt]);
        }
      }
      __builtin_amdgcn_s_setprio(0);
#pragma unroll
      for (int nt = 0; nt < 8; ++nt) s_acc[nt] = s_acc[nt] * 0.125f;

      float mx[4];
#pragma unroll
      for (int r = 0; r < 4; ++r) {
        float m = s_acc[0][r];
#pragma unroll
        for (int nt = 1; nt < 8; ++nt) m = fmaxf(m, s_acc[nt][r]);
        m = fmaxf(m, __shfl_xor(m, 1));
        m = fmaxf(m, __shfl_xor(m, 2));
        m = fmaxf(m, __shfl_xor(m, 4));
        m = fmaxf(m, __shfl_xor(m, 8));
        mx[r] = m;
      }
      bool grow = false;
#pragma unroll
      for (int r = 0; r < 4; ++r) grow = grow || (mx[r] > m_i[mt][r] + 8.f);
      if (__any(grow)) {
#pragma unroll
        for (int r = 0; r < 4; ++r) {
          float mold = m_i[mt][r];
          float mnew = fmaxf(mold, mx[r]);
          float alpha = __expf(mold - mnew);
          m_i[mt][r] = mnew;
          l_i[mt][r] *= alpha;
#pragma unroll
          for (int dt = 0; dt < 4; ++dt) o_acc[mt][dt][r] *= alpha;
        }
      }
#pragma unroll
      for (int r = 0; r < 4; ++r) {
        float mnew = m_i[mt][r];
        float rs = 0.f;
#pragma unroll
        for (int nt = 0; nt < 8; ++nt) {
          float pv = __expf(s_acc[nt][r] - mnew);
          rs += pv;
          P_lds[w][(quad * 4 + r) * 136 + nt * 16 + lrow] = (bf16)pv;
        }
        rs += __shfl_xor(rs, 1);
        rs += __shfl_xor(rs, 2);
        rs += __shfl_xor(rs, 4);
        rs += __shfl_xor(rs, 8);
        l_i[mt][r] += rs;
      }

      bf16x8 pf[4];
#pragma unroll
      for (int ks = 0; ks < 4; ++ks)
        pf[ks] = *(const bf16x8*)&P_lds[w][lrow * 136 + ks * 32 + quad * 8];
      __builtin_amdgcn_s_setprio(1);
#pragma unroll
      for (int dt = 0; dt < 4; ++dt) {
        int rv = dt * 16 + lrow;
#pragma unroll
        for (int ks = 0; ks < 4; ++ks) {
          bf16x8 vf = *(const bf16x8*)&V_lds[rv * 128 + (((ks * 4 + quad) ^ (rv & 7)) * 8)];
          o_acc[mt][dt] = mfma16(pf[ks], vf, o_acc[mt][dt]);
        }
      }
      __builtin_amdgcn_s_setprio(0);
    }
    __syncthreads();
  }

#pragma unroll
  for (int mt = 0; mt < 2; ++mt)
#pragma unroll
    for (int r = 0; r < 4; ++r) {
      float inv = 1.0f / l_i[mt][r];
      int s = qt * 128 + w * 32 + mt * 16 + quad * 4 + r;
#pragma unroll
      for (int dt = 0; dt < 4; ++dt) {
        int d = dt * 16 + lrow;
        ctx[((size_t)(bb * 1024 + s)) * 768 + h * 64 + d] = (bf16)(o_acc[mt][dt][r] * inv);
      }
    }
}

// ------- out-proj GEMM: BK=64, swizzled LDS, masked K-chunk skip (R9 form) ----
__global__ __launch_bounds__(256, 3) void gemm_out_k(
    const bf16* __restrict__ Cx, const bf16* __restrict__ Wot,
    const float* __restrict__ bo, const float* __restrict__ res,
    const float* __restrict__ mask,
    float* __restrict__ xo) {
  __shared__ __align__(16) bf16 Al[128 * 64];
  __shared__ __align__(16) bf16 Bl[128 * 64];
  int bid = blockIdx.x;
  int xcd = bid & 7, idx = bid >> 3;
  int nt = idx % 6, mt8 = idx / 6;
  int m0 = (mt8 * 8 + xcd) * 128;
  int n0 = nt * 128;
  int t = threadIdx.x, w = t >> 6, lane = t & 63, lrow = lane & 15, quad = lane >> 4;
  int wm = (w >> 1) * 64, wn = (w & 1) * 64;

  int bb = m0 >> 10;
  unsigned am = 0;
#pragma unroll
  for (int hh = 0; hh < 12; ++hh)
    am |= (mask[bb * 12 + hh] != 0.f) ? (1u << hh) : 0u;

  int srow = t >> 3;
  int sch  = (t & 7) ^ (srow & 7);
  const bf16* aptr[4];
  const bf16* bptr[4];
#pragma unroll
  for (int i = 0; i < 4; ++i) {
    aptr[i] = Cx  + (size_t)(m0 + i * 32 + srow) * 768 + sch * 8;
    bptr[i] = Wot + (size_t)(n0 + i * 32 + srow) * 768 + sch * 8;
  }
  int ra_base = wm + lrow, rb_base = wn + lrow;
  const bf16* baA[2];
  const bf16* baB[2];
#pragma unroll
  for (int ks = 0; ks < 2; ++ks) {
    baA[ks] = &Al[ra_base * 64 + (((ks * 4 + quad) ^ (ra_base & 7)) * 8)];
    baB[ks] = &Bl[rb_base * 64 + (((ks * 4 + quad) ^ (rb_base & 7)) * 8)];
  }

  f32x4 acc[4][4];
#pragma unroll
  for (int a = 0; a < 4; ++a)
#pragma unroll
    for (int b = 0; b < 4; ++b) acc[a][b] = (f32x4){0.f, 0.f, 0.f, 0.f};

  for (int k0 = 0; k0 < 768; k0 += 64) {
    if (am & (1u << (k0 >> 6))) {
#pragma unroll
      for (int i = 0; i < 4; ++i) async16(aptr[i], &Al[(i * 256 + t) * 8]);
#pragma unroll
      for (int i = 0; i < 4; ++i) async16(bptr[i], &Bl[(i * 256 + t) * 8]);
      __syncthreads();
      bf16x8 af[2][4], bfr[2][4];
#pragma unroll
      for (int ks = 0; ks < 2; ++ks)
#pragma unroll
        for (int i = 0; i < 4; ++i) {
          af[ks][i]  = *(const bf16x8*)(baA[ks] + i * 1024);
          bfr[ks][i] = *(const bf16x8*)(baB[ks] + i * 1024);
        }
#pragma unroll
      for (int ks = 0; ks < 2; ++ks)
#pragma unroll
        for (int mt = 0; mt < 4; ++mt)
#pragma unroll
          for (int nt2 = 0; nt2 < 4; ++nt2)
            acc[mt][nt2] = mfma16(af[ks][mt], bfr[ks][nt2], acc[mt][nt2]);
      __syncthreads();
    }
#pragma unroll
    for (int i = 0; i < 4; ++i) { aptr[i] += 64; bptr[i] += 64; }
  }

  float biasv[4];
#pragma unroll
  for (int nt2 = 0; nt2 < 4; ++nt2) biasv[nt2] = bo[n0 + wn + nt2 * 16 + lrow];

#pragma unroll
  for (int mt = 0; mt < 4; ++mt)
#pragma unroll
    for (int nt2 = 0; nt2 < 4; ++nt2)
#pragma unroll
      for (int r = 0; r < 4; ++r) {
        int m = m0 + wm + mt * 16 + quad * 4 + r;
        int n = n0 + wn + nt2 * 16 + lrow;
        xo[(size_t)m * 768 + n] = acc[mt][nt2][r] + biasv[nt2] + res[(size_t)m * 768 + n];
      }
}

// ---------------- LayerNorm: barrier-free, one wave per row -------------------
// 4 waves/block, each wave owns one row: 3x float4 load, 6-level shfl_xor
// reduce (no LDS, no __syncthreads, no serial finalize), 3x float4 store.
__global__ __launch_bounds__(256) void ln_k(const float* __restrict__ x,
                                            const float* __restrict__ g,
                                            const float* __restrict__ be,
                                            float* __restrict__ out) {
  int t = threadIdx.x, w = t >> 6, lane = t & 63;
  int row = blockIdx.x * 4 + w;
  const float4* xr4 = (const float4*)(x + (size_t)row * 768);
  float4 v0 = xr4[lane], v1 = xr4[lane + 64], v2 = xr4[lane + 128];
  float s  = v0.x + v0.y + v0.z + v0.w + v1.x + v1.y + v1.z + v1.w
           + v2.x + v2.y + v2.z + v2.w;
  float s2 = v0.x*v0.x + v0.y*v0.y + v0.z*v0.z + v0.w*v0.w
           + v1.x*v1.x + v1.y*v1.y + v1.z*v1.z + v1.w*v1.w
           + v2.x*v2.x + v2.y*v2.y + v2.z*v2.z + v2.w*v2.w;
#pragma unroll
  for (int off = 32; off > 0; off >>= 1) {
    s  += __shfl_xor(s, off);
    s2 += __shfl_xor(s2, off);
  }
  float mu = s * (1.0f / 768.0f);
  float var = s2 * (1.0f / 768.0f) - mu * mu;
  float rsq = rsqrtf(var + 1e-12f);
  const float4* g4 = (const float4*)g;
  const float4* b4 = (const float4*)be;
  float4* or4 = (float4*)(out + (size_t)row * 768);
  float4 gv, bv, o;
  gv = g4[lane];       bv = b4[lane];
  o.x = (v0.x - mu) * rsq * gv.x + bv.x; o.y = (v0.y - mu) * rsq * gv.y + bv.y;
  o.z = (v0.z - mu) * rsq * gv.z + bv.z; o.w = (v0.w - mu) * rsq * gv.w + bv.w;
  or4[lane] = o;
  gv = g4[lane + 64];  bv = b4[lane + 64];
  o.x = (v1.x - mu) * rsq * gv.x + bv.x; o.y = (v1.y - mu) * rsq * gv.y + bv.y;
  o.z = (v1.z - mu) * rsq * gv.z + bv.z; o.w = (v1.w - mu) * rsq * gv.w + bv.w;
  or4[lane + 64] = o;
  gv = g4[lane + 128]; bv = b4[lane + 128];
  o.x = (v2.x - mu) * rsq * gv.x + bv.x; o.y = (v2.y - mu) * rsq * gv.y + bv.y;
  o.z = (v2.z - mu) * rsq * gv.z + bv.z; o.w = (v2.w - mu) * rsq * gv.w + bv.w;
  or4[lane + 128] = o;
}

// ---------------- host launcher ----------------------------------------------
extern "C" void kernel_launch(void* const* d_in, const int* in_sizes, int n_in,
                              void* d_out, int out_size, void* d_ws, size_t ws_size,
                              hipStream_t stream) {
  const float* hs  = (const float*)d_in[0];
  const float* Wq  = (const float*)d_in[1];
  const float* bq  = (const float*)d_in[2];
  const float* Wk  = (const float*)d_in[3];
  const float* bk  = (const float*)d_in[4];
  const float* Wv  = (const float*)d_in[5];
  const float* bv  = (const float*)d_in[6];
  const float* Wr  = (const float*)d_in[7];
  const float* br  = (const float*)d_in[8];
  const float* Wo  = (const float*)d_in[9];
  const float* bo  = (const float*)d_in[10];
  const float* lng = (const float*)d_in[11];
  const float* lnb = (const float*)d_in[12];
  float* out = (float*)d_out;
  dim3 blk(256);

  // ---- workspace layout ----
  char* p = (char*)d_ws;
  float* maskp = (float*)p; p += 512;
  int*   actI  = (int*)p;   p += 256;
  float* partial = (float*)p; p += (size_t)8 * 32 * 768 * 4;   // 768 KB
  bf16* hsb  = (bf16*)p; p += (size_t)8192 * 768 * 2;          // 12.6 MB
  bf16* Wcat = (bf16*)p; p += (size_t)2304 * 768 * 2;          // 3.5 MB
  bf16* Wot  = (bf16*)p; p += (size_t)768 * 768 * 2;           // 1.2 MB

  prep_k<<<dim3(2560), blk, 0, stream>>>(hs, hsb, partial,
      Wq, Wk, Wv, Wo, Wcat, Wcat + 768 * 768, Wcat + 1536 * 768, Wot);
  router_final_k<<<dim3(8), blk, 0, stream>>>(Wr, br, partial, maskp, actI);

  size_t used_common = (size_t)(p - (char*)d_ws);
  size_t need_big = used_common + 3 * (size_t)8192 * 768 * 2;

  if (ws_size >= need_big) {
    char* qk_base = p;
    bf16* Qb  = (bf16*)p; p += (size_t)8192 * 768 * 2;
    bf16* Kb  = (bf16*)p; p += (size_t)8192 * 768 * 2;
    bf16* Vtb = (bf16*)p;
    float* Xb = (float*)qk_base;   // aliases Qb+Kb (dead after attn)
    bf16* Ctx = (bf16*)d_out;      // parks in d_out; ln_k overwrites all

    gemm_qkv_k<<<dim3(64, 3, 3), blk, 0, stream>>>(hsb, Wcat, bq, bk, bv, actI, Qb, Kb, Vtb);
    attn_k<<<dim3(48, 8), blk, 0, stream>>>(Qb, Kb, Vtb, actI, Ctx);
    gemm_out_k<<<dim3(8 * 8 * 6), blk, 0, stream>>>(Ctx, Wot, bo, hs, maskp, Xb);
    ln_k<<<dim3(2048), blk, 0, stream>>>(Xb, lng, lnb, out);
  } else {
    bf16* Qb  = (bf16*)p; p += (size_t)1024 * 768 * 2;
    bf16* Kb  = (bf16*)p; p += (size_t)1024 * 768 * 2;
    bf16* Vtb = (bf16*)p; p += (size_t)1024 * 768 * 2;
    bf16* Ctx = (bf16*)p; p += (size_t)1024 * 768 * 2;
    float* Xb = (float*)p; p += (size_t)1024 * 768 * 4;

    for (int b = 0; b < 8; ++b) {
      const bf16* hsb_b = hsb + (size_t)b * 1024 * 768;
      const float* hs_b = hs + (size_t)b * 1024 * 768;
      float* outb = out + (size_t)b * 1024 * 768;
      gemm_qkv_k<<<dim3(8, 3, 3), blk, 0, stream>>>(hsb_b, Wcat, bq, bk, bv, actI + b * 6, Qb, Kb, Vtb);
      attn_k<<<dim3(6, 8), blk, 0, stream>>>(Qb, Kb, Vtb, actI + b * 6, Ctx);
      gemm_out_k<<<dim3(8 * 1 * 6), blk, 0, stream>>>(Ctx, Wot, bo, hs_b, maskp + b * 12, Xb);
      ln_k<<<dim3(256), blk, 0, stream>>>(Xb, lng, lnb, outb);
    }
  }
}

// Round 12
// 207.818 us; speedup vs baseline: 1.5920x; 1.0142x over previous
//
#include <hip/hip_runtime.h>

typedef __bf16 bf16;
typedef __bf16 bf16x2_t __attribute__((ext_vector_type(2)));
typedef __bf16 bf16x4_t __attribute__((ext_vector_type(4)));
typedef __bf16 bf16x8 __attribute__((ext_vector_type(8)));
typedef float  f32x4  __attribute__((ext_vector_type(4)));

__device__ __forceinline__ void async16(const void* g, void* l) {
  __builtin_amdgcn_global_load_lds(
      (__attribute__((address_space(1))) void*)(g),
      (__attribute__((address_space(3))) void*)(l), 16, 0, 0);
}

__device__ __forceinline__ f32x4 mfma16(bf16x8 a, bf16x8 b, f32x4 c) {
  return __builtin_amdgcn_mfma_f32_16x16x32_bf16(a, b, c, 0, 0, 0);
}

// ------- fused prep: 4 weight transposes + hs cvt + router partial sums -------
__global__ __launch_bounds__(256) void prep_k(
    const float* __restrict__ hs, bf16* __restrict__ hsb, float* __restrict__ partial,
    const float* __restrict__ s0, const float* __restrict__ s1,
    const float* __restrict__ s2, const float* __restrict__ s3,
    bf16* __restrict__ d0, bf16* __restrict__ d1,
    bf16* __restrict__ d2, bf16* __restrict__ d3) {
  __shared__ bf16 tile[32][33];
  int id = blockIdx.x;
  int t = threadIdx.x;
  if (id < 2304) {
    int z = id / 576, rem = id % 576;
    int by = rem / 24, bx = rem % 24;
    const float* in = (z == 0) ? s0 : (z == 1) ? s1 : (z == 2) ? s2 : s3;
    bf16* out       = (z == 0) ? d0 : (z == 1) ? d1 : (z == 2) ? d2 : d3;
    int c0 = bx * 32, r0 = by * 32;
#pragma unroll
    for (int i = 0; i < 4; ++i) {
      int idx = t + i * 256;
      int r = idx >> 5, c = idx & 31;
      tile[r][c] = (bf16)in[(size_t)(r0 + r) * 768 + (c0 + c)];
    }
    __syncthreads();
#pragma unroll
    for (int i = 0; i < 4; ++i) {
      int idx = t + i * 256;
      int r = idx >> 5, c = idx & 31;
      out[(size_t)(c0 + r) * 768 + (r0 + c)] = tile[c][r];
    }
  } else {
    int id2 = id - 2304;
    int b = id2 & 7, g = id2 >> 3;
    if (t >= 192) return;
    const float* p = hs  + ((size_t)b * 1024 + g * 32) * 768 + t * 4;
    bf16*        q = hsb + ((size_t)b * 1024 + g * 32) * 768 + t * 4;
    float4 a = {0.f, 0.f, 0.f, 0.f};
    for (int s = 0; s < 32; ++s) {
      float4 v = *(const float4*)(p + (size_t)s * 768);
      a.x += v.x; a.y += v.y; a.z += v.z; a.w += v.w;
      bf16x4_t o;
      o[0] = (bf16)v.x; o[1] = (bf16)v.y; o[2] = (bf16)v.z; o[3] = (bf16)v.w;
      *(bf16x4_t*)(q + (size_t)s * 768) = o;
    }
    *(float4*)(partial + ((size_t)b * 32 + g) * 768 + t * 4) = a;
  }
}

// ---- router stage 2: mean -> logits (parallel dot) -> top-6 mask + head list -
__global__ __launch_bounds__(256) void router_final_k(const float* __restrict__ Wr,
                                                      const float* __restrict__ br,
                                                      const float* __restrict__ partial,
                                                      float* __restrict__ mask,
                                                      int* __restrict__ actH) {
  int b = blockIdx.x, t = threadIdx.x;
  int w = t >> 6;
  __shared__ float mean_s[768];
  __shared__ float red[4][12];
  __shared__ float lg[12];
  for (int c = t; c < 768; c += 256) {
    float a = 0.f;
    for (int g = 0; g < 32; ++g) a += partial[((size_t)b * 32 + g) * 768 + c];
    mean_s[c] = a * (1.0f / 1024.0f);
  }
  __syncthreads();
  float a[12];
#pragma unroll
  for (int h = 0; h < 12; ++h) a[h] = 0.f;
#pragma unroll
  for (int j = 0; j < 3; ++j) {
    int c = t + j * 256;
    float m = mean_s[c];
    const float* wr = Wr + c * 12;
#pragma unroll
    for (int h = 0; h < 12; ++h) a[h] += m * wr[h];
  }
#pragma unroll
  for (int off = 1; off < 64; off <<= 1)
#pragma unroll
    for (int h = 0; h < 12; ++h) a[h] += __shfl_xor(a[h], off);
  if ((t & 63) == 0)
#pragma unroll
    for (int h = 0; h < 12; ++h) red[w][h] = a[h];
  __syncthreads();
  if (t == 0) {
#pragma unroll
    for (int h = 0; h < 12; ++h)
      lg[h] = br[h] + red[0][h] + red[1][h] + red[2][h] + red[3][h];
    unsigned chosen = 0;
    for (int j = 0; j < 6; ++j) {
      int bi = -1; float bv = -1e30f;
      for (int h = 0; h < 12; ++h)
        if (!((chosen >> h) & 1) && lg[h] > bv) { bv = lg[h]; bi = h; }
      chosen |= 1u << bi;
    }
    int k = 0;
    for (int h = 0; h < 12; ++h) {
      mask[b * 12 + h] = ((chosen >> h) & 1) ? 1.f : 0.f;
      if ((chosen >> h) & 1) actH[b * 6 + (k++)] = h;
    }
  }
}

// ------- QKV GEMM over ACTIVE head PAIRS: full 128x128 tiles ------------------
__global__ __launch_bounds__(256, 3) void gemm_qkv_k(
    const bf16* __restrict__ X, const bf16* __restrict__ Wcat,
    const float* __restrict__ bq, const float* __restrict__ bk, const float* __restrict__ bv,
    const int* __restrict__ actH,
    bf16* __restrict__ Qo, bf16* __restrict__ Ko, bf16* __restrict__ Vto) {
  __shared__ __align__(16) bf16 Al[128 * 64];
  __shared__ __align__(16) bf16 Bl[128 * 64];
  int mt64 = blockIdx.x;
  int sp   = blockIdx.y;
  int z    = blockIdx.z;
  int b    = mt64 >> 3;
  int h0   = actH[b * 6 + sp * 2];
  int h1   = actH[b * 6 + sp * 2 + 1];
  int m0   = mt64 * 128;

  const float* bia = (z == 0) ? bq : (z == 1) ? bk : bv;
  int t = threadIdx.x, w = t >> 6, lane = t & 63, lrow = lane & 15, quad = lane >> 4;
  int wm = (w >> 1) * 64, wn = (w & 1) * 64;

  int srow = t >> 3;
  int sch  = (t & 7) ^ (srow & 7);
  const bf16* aptr[4];
  const bf16* bptr[4];
#pragma unroll
  for (int i = 0; i < 4; ++i) {
    aptr[i] = X + (size_t)(m0 + i * 32 + srow) * 768 + sch * 8;
    int hh = (i < 2) ? h0 : h1;
    int rr = (i & 1) * 32 + srow;
    bptr[i] = Wcat + (size_t)(z * 768 + hh * 64 + rr) * 768 + sch * 8;
  }

  int ra_base = wm + lrow, rb_base = wn + lrow;
  const bf16* baA[2];
  const bf16* baB[2];
#pragma unroll
  for (int ks = 0; ks < 2; ++ks) {
    baA[ks] = &Al[ra_base * 64 + (((ks * 4 + quad) ^ (ra_base & 7)) * 8)];
    baB[ks] = &Bl[rb_base * 64 + (((ks * 4 + quad) ^ (rb_base & 7)) * 8)];
  }

  f32x4 acc[4][4];
#pragma unroll
  for (int a = 0; a < 4; ++a)
#pragma unroll
    for (int c = 0; c < 4; ++c) acc[a][c] = (f32x4){0.f, 0.f, 0.f, 0.f};

  for (int k0 = 0; k0 < 768; k0 += 64) {
#pragma unroll
    for (int i = 0; i < 4; ++i) {
      async16(aptr[i], &Al[(i * 256 + t) * 8]);
      aptr[i] += 64;
    }
#pragma unroll
    for (int i = 0; i < 4; ++i) {
      async16(bptr[i], &Bl[(i * 256 + t) * 8]);
      bptr[i] += 64;
    }
    __syncthreads();
    bf16x8 af[2][4], bfr[2][4];
#pragma unroll
    for (int ks = 0; ks < 2; ++ks)
#pragma unroll
      for (int i = 0; i < 4; ++i) {
        af[ks][i]  = *(const bf16x8*)(baA[ks] + i * 1024);
        bfr[ks][i] = *(const bf16x8*)(baB[ks] + i * 1024);
      }
#pragma unroll
    for (int ks = 0; ks < 2; ++ks)
#pragma unroll
      for (int mt = 0; mt < 4; ++mt)
#pragma unroll
        for (int nt2 = 0; nt2 < 4; ++nt2)
          acc[mt][nt2] = mfma16(af[ks][mt], bfr[ks][nt2], acc[mt][nt2]);
    __syncthreads();
  }

  float biasv[4];
#pragma unroll
  for (int nt2 = 0; nt2 < 4; ++nt2) {
    int nl = wn + nt2 * 16 + lrow;
    int hh = (nl >> 6) ? h1 : h0;
    biasv[nt2] = bia[hh * 64 + (nl & 63)];
  }

  if (z == 2) {
#pragma unroll
    for (int mt = 0; mt < 4; ++mt)
#pragma unroll
      for (int nt2 = 0; nt2 < 4; ++nt2) {
        int s = (m0 + wm + mt * 16 + quad * 4) & 1023;
        int nl = wn + nt2 * 16 + lrow;
        int hh = (nl >> 6) ? h1 : h0;
        int d = nl & 63;
        bf16x4_t pk;
#pragma unroll
        for (int r = 0; r < 4; ++r) pk[r] = (bf16)(acc[mt][nt2][r] + biasv[nt2]);
        *(bf16x4_t*)&Vto[(((size_t)b * 12 + hh) * 64 + d) * 1024 + s] = pk;
      }
  } else {
    bf16* Out = (z == 0) ? Qo : Ko;
#pragma unroll
    for (int mt = 0; mt < 4; ++mt)
#pragma unroll
      for (int nt2 = 0; nt2 < 4; ++nt2)
#pragma unroll
        for (int r = 0; r < 4; ++r) {
          int s = (m0 + wm + mt * 16 + quad * 4 + r) & 1023;
          int nl = wn + nt2 * 16 + lrow;
          int hh = (nl >> 6) ? h1 : h0;
          int d = nl & 63;
          Out[(((size_t)b * 12 + hh) * 1024 + s) * 64 + d] =
              (bf16)(acc[mt][nt2][r] + biasv[nt2]);
        }
  }
}

// ---------------- flash attention, KV-SPLIT x2 (R9 structure + T5 + T13) ------
// Per-block latency-chain model (R0-R11): kernel time ~= per-block time ~=
// nkt x chain. blockIdx.z in {0,1} halves the key range -> 4 kt iterations,
// 768 blocks (= 3/CU LDS capacity, all co-resident). Blocks write unnormalized
// partials (o, m, l) -- exact under defer-max since (o,l) are consistent with
// the stored m -- and combine_k merges the two splits.
__global__ __launch_bounds__(256, 3) void attn_k(
    const bf16* __restrict__ Q, const bf16* __restrict__ K, const bf16* __restrict__ Vt,
    const int* __restrict__ actH,
    bf16* __restrict__ opart, float* __restrict__ mpart, float* __restrict__ lpart,
    int nbh) {
  int ai = blockIdx.x, qt = blockIdx.y, z = blockIdx.z;
  int bb = ai / 6, slot = ai - bb * 6;
  int h = actH[bb * 6 + slot];
  int bh = bb * 12 + h;
  int t = threadIdx.x, w = t >> 6, lane = t & 63, lrow = lane & 15, quad = lane >> 4;

  __shared__ __align__(16) bf16 K_lds[128 * 64];
  __shared__ __align__(16) bf16 V_lds[64 * 128];
  __shared__ __align__(16) bf16 P_lds[4][16 * 136];

  const bf16* Qh = Q  + (size_t)bh * 65536;
  const bf16* Kh = K  + (size_t)bh * 65536 + (size_t)z * 32768;  // z*512 keys
  const bf16* Vh = Vt + (size_t)bh * 65536;
  int vcol0 = z * 512;

  bf16x8 qf[2][2];
#pragma unroll
  for (int mt = 0; mt < 2; ++mt)
#pragma unroll
    for (int ks = 0; ks < 2; ++ks)
      qf[mt][ks] = *(const bf16x8*)&Qh[(size_t)(qt * 128 + w * 32 + mt * 16 + lrow) * 64 + ks * 32 + quad * 8];

  f32x4 o_acc[2][4];
  float m_i[2][4], l_i[2][4];
#pragma unroll
  for (int mt = 0; mt < 2; ++mt) {
#pragma unroll
    for (int dt = 0; dt < 4; ++dt) o_acc[mt][dt] = (f32x4){0.f, 0.f, 0.f, 0.f};
#pragma unroll
    for (int r = 0; r < 4; ++r) { m_i[mt][r] = -INFINITY; l_i[mt][r] = 0.f; }
  }

  for (int kt = 0; kt < 4; ++kt) {
#pragma unroll
    for (int i = 0; i < 4; ++i) {
      int c = i * 256 + t;
      int r = c >> 3, ch = (c & 7) ^ (r & 7);
      async16(Kh + (size_t)kt * 8192 + r * 64 + ch * 8, &K_lds[c * 8]);
    }
#pragma unroll
    for (int i = 0; i < 4; ++i) {
      int c = i * 256 + t;
      int r = c >> 4, ch = (c & 15) ^ (r & 7);
      async16(Vh + (size_t)r * 1024 + vcol0 + kt * 128 + ch * 8, &V_lds[c * 8]);
    }
    __syncthreads();

#pragma unroll
    for (int mt = 0; mt < 2; ++mt) {
      f32x4 s_acc[8];
#pragma unroll
      for (int nt = 0; nt < 8; ++nt) s_acc[nt] = (f32x4){0.f, 0.f, 0.f, 0.f};
      __builtin_amdgcn_s_setprio(1);
#pragma unroll
      for (int nt = 0; nt < 8; ++nt) {
        int rb = nt * 16 + lrow;
#pragma unroll
        for (int ks = 0; ks < 2; ++ks) {
          bf16x8 kf = *(const bf16x8*)&K_lds[rb * 64 + (((ks * 4 + quad) ^ (rb & 7)) * 8)];
          s_acc[nt] = mfma16(qf[mt][ks], kf, s_acc[nt]);
        }
      }
      __builtin_amdgcn_s_setprio(0);
#pragma unroll
      for (int nt = 0; nt < 8; ++nt) s_acc[nt] = s_acc[nt] * 0.125f;

      float mx[4];
#pragma unroll
      for (int r = 0; r < 4; ++r) {
        float m = s_acc[0][r];
#pragma unroll
        for (int nt = 1; nt < 8; ++nt) m = fmaxf(m, s_acc[nt][r]);
        m = fmaxf(m, __shfl_xor(m, 1));
        m = fmaxf(m, __shfl_xor(m, 2));
        m = fmaxf(m, __shfl_xor(m, 4));
        m = fmaxf(m, __shfl_xor(m, 8));
        mx[r] = m;
      }
      bool grow = false;
#pragma unroll
      for (int r = 0; r < 4; ++r) grow = grow || (mx[r] > m_i[mt][r] + 8.f);
      if (__any(grow)) {
#pragma unroll
        for (int r = 0; r < 4; ++r) {
          float mold = m_i[mt][r];
          float mnew = fmaxf(mold, mx[r]);
          float alpha = __expf(mold - mnew);
          m_i[mt][r] = mnew;
          l_i[mt][r] *= alpha;
#pragma unroll
          for (int dt = 0; dt < 4; ++dt) o_acc[mt][dt][r] *= alpha;
        }
      }
#pragma unroll
      for (int r = 0; r < 4; ++r) {
        float mnew = m_i[mt][r];
        float rs = 0.f;
#pragma unroll
        for (int nt = 0; nt < 8; ++nt) {
          float pv = __expf(s_acc[nt][r] - mnew);
          rs += pv;
          P_lds[w][(quad * 4 + r) * 136 + nt * 16 + lrow] = (bf16)pv;
        }
        rs += __shfl_xor(rs, 1);
        rs += __shfl_xor(rs, 2);
        rs += __shfl_xor(rs, 4);
        rs += __shfl_xor(rs, 8);
        l_i[mt][r] += rs;
      }

      bf16x8 pf[4];
#pragma unroll
      for (int ks = 0; ks < 4; ++ks)
        pf[ks] = *(const bf16x8*)&P_lds[w][lrow * 136 + ks * 32 + quad * 8];
      __builtin_amdgcn_s_setprio(1);
#pragma unroll
      for (int dt = 0; dt < 4; ++dt) {
        int rv = dt * 16 + lrow;
#pragma unroll
        for (int ks = 0; ks < 4; ++ks) {
          bf16x8 vf = *(const bf16x8*)&V_lds[rv * 128 + (((ks * 4 + quad) ^ (rv & 7)) * 8)];
          o_acc[mt][dt] = mfma16(pf[ks], vf, o_acc[mt][dt]);
        }
      }
      __builtin_amdgcn_s_setprio(0);
    }
    __syncthreads();
  }

  // ---- write unnormalized partials (o, m, l) for this split ----
  size_t tile = ((size_t)(z * nbh + ai) * 8 + qt);
#pragma unroll
  for (int mt = 0; mt < 2; ++mt)
#pragma unroll
    for (int r = 0; r < 4; ++r) {
      int srow = w * 32 + mt * 16 + quad * 4 + r;
      if (lrow == 0) {
        mpart[tile * 128 + srow] = m_i[mt][r];
        lpart[tile * 128 + srow] = l_i[mt][r];
      }
#pragma unroll
      for (int dt = 0; dt < 4; ++dt)
        opart[(tile * 128 + srow) * 64 + dt * 16 + lrow] = (bf16)o_acc[mt][dt][r];
    }
}

// ---------------- combine the two KV-splits into ctx --------------------------
__global__ __launch_bounds__(256) void combine_k(
    const bf16* __restrict__ opart, const float* __restrict__ mpart,
    const float* __restrict__ lpart, const int* __restrict__ actH,
    bf16* __restrict__ ctx, int nbh) {
  int ai = blockIdx.x, qt = blockIdx.y;
  int bb = ai / 6, slot = ai - bb * 6;
  int h = actH[bb * 6 + slot];
  int t = threadIdx.x, w = t >> 6, lane = t & 63;
  size_t t1 = ((size_t)ai * 8 + qt) * 128;
  size_t t2 = ((size_t)(nbh + ai) * 8 + qt) * 128;
  for (int i = 0; i < 32; ++i) {
    int row = w * 32 + i;
    float m1 = mpart[t1 + row], l1 = lpart[t1 + row];
    float m2 = mpart[t2 + row], l2 = lpart[t2 + row];
    float M = fmaxf(m1, m2);
    float a1 = __expf(m1 - M), a2 = __expf(m2 - M);
    float inv = 1.0f / (l1 * a1 + l2 * a2);
    float o1 = (float)opart[(t1 + row) * 64 + lane];
    float o2 = (float)opart[(t2 + row) * 64 + lane];
    int s = qt * 128 + row;
    ctx[((size_t)(bb * 1024 + s)) * 768 + h * 64 + lane] =
        (bf16)((o1 * a1 + o2 * a2) * inv);
  }
}

// ------- out-proj GEMM: BK=64, swizzled LDS, masked K-chunk skip --------------
__global__ __launch_bounds__(256, 3) void gemm_out_k(
    const bf16* __restrict__ Cx, const bf16* __restrict__ Wot,
    const float* __restrict__ bo, const float* __restrict__ res,
    const float* __restrict__ mask,
    float* __restrict__ xo) {
  __shared__ __align__(16) bf16 Al[128 * 64];
  __shared__ __align__(16) bf16 Bl[128 * 64];
  int bid = blockIdx.x;
  int xcd = bid & 7, idx = bid >> 3;
  int nt = idx % 6, mt8 = idx / 6;
  int m0 = (mt8 * 8 + xcd) * 128;
  int n0 = nt * 128;
  int t = threadIdx.x, w = t >> 6, lane = t & 63, lrow = lane & 15, quad = lane >> 4;
  int wm = (w >> 1) * 64, wn = (w & 1) * 64;

  int bb = m0 >> 10;
  unsigned am = 0;
#pragma unroll
  for (int hh = 0; hh < 12; ++hh)
    am |= (mask[bb * 12 + hh] != 0.f) ? (1u << hh) : 0u;

  int srow = t >> 3;
  int sch  = (t & 7) ^ (srow & 7);
  const bf16* aptr[4];
  const bf16* bptr[4];
#pragma unroll
  for (int i = 0; i < 4; ++i) {
    aptr[i] = Cx  + (size_t)(m0 + i * 32 + srow) * 768 + sch * 8;
    bptr[i] = Wot + (size_t)(n0 + i * 32 + srow) * 768 + sch * 8;
  }
  int ra_base = wm + lrow, rb_base = wn + lrow;
  const bf16* baA[2];
  const bf16* baB[2];
#pragma unroll
  for (int ks = 0; ks < 2; ++ks) {
    baA[ks] = &Al[ra_base * 64 + (((ks * 4 + quad) ^ (ra_base & 7)) * 8)];
    baB[ks] = &Bl[rb_base * 64 + (((ks * 4 + quad) ^ (rb_base & 7)) * 8)];
  }

  f32x4 acc[4][4];
#pragma unroll
  for (int a = 0; a < 4; ++a)
#pragma unroll
    for (int b = 0; b < 4; ++b) acc[a][b] = (f32x4){0.f, 0.f, 0.f, 0.f};

  for (int k0 = 0; k0 < 768; k0 += 64) {
    if (am & (1u << (k0 >> 6))) {
#pragma unroll
      for (int i = 0; i < 4; ++i) async16(aptr[i], &Al[(i * 256 + t) * 8]);
#pragma unroll
      for (int i = 0; i < 4; ++i) async16(bptr[i], &Bl[(i * 256 + t) * 8]);
      __syncthreads();
      bf16x8 af[2][4], bfr[2][4];
#pragma unroll
      for (int ks = 0; ks < 2; ++ks)
#pragma unroll
        for (int i = 0; i < 4; ++i) {
          af[ks][i]  = *(const bf16x8*)(baA[ks] + i * 1024);
          bfr[ks][i] = *(const bf16x8*)(baB[ks] + i * 1024);
        }
#pragma unroll
      for (int ks = 0; ks < 2; ++ks)
#pragma unroll
        for (int mt = 0; mt < 4; ++mt)
#pragma unroll
          for (int nt2 = 0; nt2 < 4; ++nt2)
            acc[mt][nt2] = mfma16(af[ks][mt], bfr[ks][nt2], acc[mt][nt2]);
      __syncthreads();
    }
#pragma unroll
    for (int i = 0; i < 4; ++i) { aptr[i] += 64; bptr[i] += 64; }
  }

  float biasv[4];
#pragma unroll
  for (int nt2 = 0; nt2 < 4; ++nt2) biasv[nt2] = bo[n0 + wn + nt2 * 16 + lrow];

#pragma unroll
  for (int mt = 0; mt < 4; ++mt)
#pragma unroll
    for (int nt2 = 0; nt2 < 4; ++nt2)
#pragma unroll
      for (int r = 0; r < 4; ++r) {
        int m = m0 + wm + mt * 16 + quad * 4 + r;
        int n = n0 + wn + nt2 * 16 + lrow;
        xo[(size_t)m * 768 + n] = acc[mt][nt2][r] + biasv[nt2] + res[(size_t)m * 768 + n];
      }
}

// ---------------- LayerNorm: barrier-free, one wave per row -------------------
__global__ __launch_bounds__(256) void ln_k(const float* __restrict__ x,
                                            const float* __restrict__ g,
                                            const float* __restrict__ be,
                                            float* __restrict__ out) {
  int t = threadIdx.x, w = t >> 6, lane = t & 63;
  int row = blockIdx.x * 4 + w;
  const float4* xr4 = (const float4*)(x + (size_t)row * 768);
  float4 v0 = xr4[lane], v1 = xr4[lane + 64], v2 = xr4[lane + 128];
  float s  = v0.x + v0.y + v0.z + v0.w + v1.x + v1.y + v1.z + v1.w
           + v2.x + v2.y + v2.z + v2.w;
  float s2 = v0.x*v0.x + v0.y*v0.y + v0.z*v0.z + v0.w*v0.w
           + v1.x*v1.x + v1.y*v1.y + v1.z*v1.z + v1.w*v1.w
           + v2.x*v2.x + v2.y*v2.y + v2.z*v2.z + v2.w*v2.w;
#pragma unroll
  for (int off = 32; off > 0; off >>= 1) {
    s  += __shfl_xor(s, off);
    s2 += __shfl_xor(s2, off);
  }
  float mu = s * (1.0f / 768.0f);
  float var = s2 * (1.0f / 768.0f) - mu * mu;
  float rsq = rsqrtf(var + 1e-12f);
  const float4* g4 = (const float4*)g;
  const float4* b4 = (const float4*)be;
  float4* or4 = (float4*)(out + (size_t)row * 768);
  float4 gv, bv, o;
  gv = g4[lane];       bv = b4[lane];
  o.x = (v0.x - mu) * rsq * gv.x + bv.x; o.y = (v0.y - mu) * rsq * gv.y + bv.y;
  o.z = (v0.z - mu) * rsq * gv.z + bv.z; o.w = (v0.w - mu) * rsq * gv.w + bv.w;
  or4[lane] = o;
  gv = g4[lane + 64];  bv = b4[lane + 64];
  o.x = (v1.x - mu) * rsq * gv.x + bv.x; o.y = (v1.y - mu) * rsq * gv.y + bv.y;
  o.z = (v1.z - mu) * rsq * gv.z + bv.z; o.w = (v1.w - mu) * rsq * gv.w + bv.w;
  or4[lane + 64] = o;
  gv = g4[lane + 128]; bv = b4[lane + 128];
  o.x = (v2.x - mu) * rsq * gv.x + bv.x; o.y = (v2.y - mu) * rsq * gv.y + bv.y;
  o.z = (v2.z - mu) * rsq * gv.z + bv.z; o.w = (v2.w - mu) * rsq * gv.w + bv.w;
  or4[lane + 128] = o;
}

// ---------------- host launcher ----------------------------------------------
extern "C" void kernel_launch(void* const* d_in, const int* in_sizes, int n_in,
                              void* d_out, int out_size, void* d_ws, size_t ws_size,
                              hipStream_t stream) {
  const float* hs  = (const float*)d_in[0];
  const float* Wq  = (const float*)d_in[1];
  const float* bq  = (const float*)d_in[2];
  const float* Wk  = (const float*)d_in[3];
  const float* bk  = (const float*)d_in[4];
  const float* Wv  = (const float*)d_in[5];
  const float* bv  = (const float*)d_in[6];
  const float* Wr  = (const float*)d_in[7];
  const float* br  = (const float*)d_in[8];
  const float* Wo  = (const float*)d_in[9];
  const float* bo  = (const float*)d_in[10];
  const float* lng = (const float*)d_in[11];
  const float* lnb = (const float*)d_in[12];
  float* out = (float*)d_out;
  dim3 blk(256);

  // ---- workspace layout ----
  char* p = (char*)d_ws;
  float* maskp = (float*)p; p += 512;
  int*   actI  = (int*)p;   p += 256;
  float* partial = (float*)p; p += (size_t)8 * 32 * 768 * 4;   // 768 KB
  bf16* hsb  = (bf16*)p; p += (size_t)8192 * 768 * 2;          // 12.6 MB (doubles as Ctx)
  bf16* Wcat = (bf16*)p; p += (size_t)2304 * 768 * 2;          // 3.5 MB
  bf16* Wot  = (bf16*)p; p += (size_t)768 * 768 * 2;           // 1.2 MB

  prep_k<<<dim3(2560), blk, 0, stream>>>(hs, hsb, partial,
      Wq, Wk, Wv, Wo, Wcat, Wcat + 768 * 768, Wcat + 1536 * 768, Wot);
  router_final_k<<<dim3(8), blk, 0, stream>>>(Wr, br, partial, maskp, actI);

  size_t used_common = (size_t)(p - (char*)d_ws);
  size_t need_big = used_common + 3 * (size_t)8192 * 768 * 2;

  if (ws_size >= need_big) {
    char* qk_base = p;
    bf16* Qb  = (bf16*)p; p += (size_t)8192 * 768 * 2;
    bf16* Kb  = (bf16*)p; p += (size_t)8192 * 768 * 2;
    bf16* Vtb = (bf16*)p;
    float* Xb = (float*)qk_base;     // aliases Qb+Kb (dead after attn+combine)
    bf16* Ctx = hsb;                 // hsb dead after gemm_qkv (R10-verified)
    // attn partials park in d_out (dead until ln_k writes it at the end):
    bf16*  opart = (bf16*)d_out;                                   // 12.6 MB
    float* mpart = (float*)((char*)d_out + (size_t)13 * 1024 * 1024);
    float* lpart = mpart + 2 * 48 * 8 * 128;                       // ~0.4 MB each

    gemm_qkv_k<<<dim3(64, 3, 3), blk, 0, stream>>>(hsb, Wcat, bq, bk, bv, actI, Qb, Kb, Vtb);
    attn_k<<<dim3(48, 8, 2), blk, 0, stream>>>(Qb, Kb, Vtb, actI, opart, mpart, lpart, 48);
    combine_k<<<dim3(48, 8), blk, 0, stream>>>(opart, mpart, lpart, actI, Ctx, 48);
    gemm_out_k<<<dim3(8 * 8 * 6), blk, 0, stream>>>(Ctx, Wot, bo, hs, maskp, Xb);
    ln_k<<<dim3(2048), blk, 0, stream>>>(Xb, lng, lnb, out);
  } else {
    bf16* Qb  = (bf16*)p; p += (size_t)1024 * 768 * 2;
    bf16* Kb  = (bf16*)p; p += (size_t)1024 * 768 * 2;
    bf16* Vtb = (bf16*)p; p += (size_t)1024 * 768 * 2;
    bf16* Ctx = (bf16*)p; p += (size_t)1024 * 768 * 2;
    float* Xb = (float*)p; p += (size_t)1024 * 768 * 4;
    bf16*  opart = (bf16*)p; p += (size_t)2 * 6 * 8 * 128 * 64 * 2;  // 1.6 MB
    float* mpart = (float*)p; p += (size_t)2 * 6 * 8 * 128 * 4;
    float* lpart = (float*)p; p += (size_t)2 * 6 * 8 * 128 * 4;

    for (int b = 0; b < 8; ++b) {
      const bf16* hsb_b = hsb + (size_t)b * 1024 * 768;
      const float* hs_b = hs + (size_t)b * 1024 * 768;
      float* outb = out + (size_t)b * 1024 * 768;
      gemm_qkv_k<<<dim3(8, 3, 3), blk, 0, stream>>>(hsb_b, Wcat, bq, bk, bv, actI + b * 6, Qb, Kb, Vtb);
      attn_k<<<dim3(6, 8, 2), blk, 0, stream>>>(Qb, Kb, Vtb, actI + b * 6, opart, mpart, lpart, 6);
      combine_k<<<dim3(6, 8), blk, 0, stream>>>(opart, mpart, lpart, actI + b * 6, Ctx, 6);
      gemm_out_k<<<dim3(8 * 1 * 6), blk, 0, stream>>>(Ctx, Wot, bo, hs_b, maskp + b * 12, Xb);
      ln_k<<<dim3(256), blk, 0, stream>>>(Xb, lng, lnb, outb);
    }
  }
}